// Round 1
// baseline (3279.411 us; speedup 1.0000x reference)
//
#include <hip/hip_runtime.h>
#include <hip/hip_bf16.h>
#include <math.h>

// Problem constants (B=2, T=2048, C=1024, H=16, hs=64)
#define B_  2
#define T_  2048
#define C_  1024
#define H_  16
#define HS_ 64
#define M_  (B_ * T_)   // 4096 rows in the flattened [B*T, C] view

// ---------------------------------------------------------------------------
// Generic fp32 GEMM: Y = A[M,K] @ W[K,N] (+ bias[N]) (+ resid[M,N]) (ReLU?)
// 64x64 tile, BK=16, 256 threads, 4x4 register microtile.
// ---------------------------------------------------------------------------
template<bool RELU, bool RESID>
__global__ __launch_bounds__(256)
void gemm_f32(const float* __restrict__ A, const float* __restrict__ W,
              const float* __restrict__ bias, const float* __restrict__ resid,
              float* __restrict__ Y, int M, int N, int K) {
    const int BM = 64, BN = 64, BK = 16;
    __shared__ float As[BK][BM];   // A stored transposed: As[k][m]
    __shared__ float Bs[BK][BN];   // B row-major: Bs[k][n]

    const int tid  = threadIdx.x;
    const int brow = blockIdx.y * BM;
    const int bcol = blockIdx.x * BN;
    const int ty = tid >> 4;          // 0..15 -> row group
    const int tx = tid & 15;          // 0..15 -> col group

    // staging indices
    const int am = tid >> 2;          // 0..63  (row within A tile)
    const int ak = (tid & 3) << 2;    // 0,4,8,12
    const int bk = tid >> 4;          // 0..15  (row within B tile)
    const int bn = (tid & 15) << 2;   // 0..60

    float acc[4][4] = {};

    for (int k0 = 0; k0 < K; k0 += BK) {
        float4 av = *(const float4*)&A[(size_t)(brow + am) * K + k0 + ak];
        As[ak + 0][am] = av.x;
        As[ak + 1][am] = av.y;
        As[ak + 2][am] = av.z;
        As[ak + 3][am] = av.w;
        float4 bv = *(const float4*)&W[(size_t)(k0 + bk) * N + bcol + bn];
        *(float4*)&Bs[bk][bn] = bv;
        __syncthreads();

        #pragma unroll
        for (int kk = 0; kk < BK; ++kk) {
            float a[4], b[4];
            #pragma unroll
            for (int i = 0; i < 4; ++i) a[i] = As[kk][ty * 4 + i];
            #pragma unroll
            for (int j = 0; j < 4; ++j) b[j] = Bs[kk][tx * 4 + j];
            #pragma unroll
            for (int i = 0; i < 4; ++i)
                #pragma unroll
                for (int j = 0; j < 4; ++j)
                    acc[i][j] = fmaf(a[i], b[j], acc[i][j]);
        }
        __syncthreads();
    }

    #pragma unroll
    for (int i = 0; i < 4; ++i) {
        const int r = brow + ty * 4 + i;
        #pragma unroll
        for (int j = 0; j < 4; ++j) {
            const int c = bcol + tx * 4 + j;
            float v = acc[i][j];
            if (bias)  v += bias[c];
            if (RESID) v += resid[(size_t)r * N + c];
            if (RELU)  v = fmaxf(v, 0.f);
            Y[(size_t)r * N + c] = v;
        }
    }
}

// ---------------------------------------------------------------------------
// Flash attention fp32 (causal). One block per (q-tile of 64 rows, head, batch).
// q/k/v are [M_, C_] buffers; head h occupies columns [h*64, h*64+64).
// scale = C^-0.5 = 1/32 (reference scales by full model dim, not head dim).
// ---------------------------------------------------------------------------
__global__ __launch_bounds__(256)
void attn_f32(const float* __restrict__ q, const float* __restrict__ k,
              const float* __restrict__ v, float* __restrict__ o) {
    const int BQ = 64, BKV = 64, D = 64;
    __shared__ float Qs[BQ][D + 1];
    __shared__ float Ks[BKV][D + 1];
    __shared__ float Vs[BKV][D + 1];
    __shared__ float Ss[BQ][BKV + 1];

    const int tid = threadIdx.x;
    const int qt = blockIdx.x, h = blockIdx.y, b = blockIdx.z;
    const float scale = 0.03125f;  // 1024^-0.5

    const size_t base = (size_t)b * T_ * C_ + (size_t)h * HS_;

    // load Q tile (64x64), coalesced float4
    for (int t = 0; t < 4; ++t) {
        int c4  = tid + t * 256;          // chunk id 0..1023
        int row = c4 >> 4;                // /16
        int col = (c4 & 15) << 2;
        float4 qv = *(const float4*)&q[base + (size_t)(qt * BQ + row) * C_ + col];
        Qs[row][col + 0] = qv.x; Qs[row][col + 1] = qv.y;
        Qs[row][col + 2] = qv.z; Qs[row][col + 3] = qv.w;
    }

    const int r  = tid >> 2;          // 0..63 : q row within tile
    const int j0 = (tid & 3) << 4;    // 0,16,32,48 : S column group
    const int d0 = j0;                // output dim group (reuse mapping)
    const int qrow = qt * BQ + r;

    float m = -INFINITY, l = 0.f;
    float oacc[16];
    #pragma unroll
    for (int i = 0; i < 16; ++i) oacc[i] = 0.f;

    for (int kt = 0; kt <= qt; ++kt) {
        // stage K,V tiles
        for (int t = 0; t < 4; ++t) {
            int c4  = tid + t * 256;
            int row = c4 >> 4;
            int col = (c4 & 15) << 2;
            float4 kv = *(const float4*)&k[base + (size_t)(kt * BKV + row) * C_ + col];
            Ks[row][col + 0] = kv.x; Ks[row][col + 1] = kv.y;
            Ks[row][col + 2] = kv.z; Ks[row][col + 3] = kv.w;
            float4 vv = *(const float4*)&v[base + (size_t)(kt * BKV + row) * C_ + col];
            Vs[row][col + 0] = vv.x; Vs[row][col + 1] = vv.y;
            Vs[row][col + 2] = vv.z; Vs[row][col + 3] = vv.w;
        }
        __syncthreads();

        // S(r, j0..j0+15) = Q[r,:] . K[j,:]
        float s[16];
        #pragma unroll
        for (int jj = 0; jj < 16; ++jj) s[jj] = 0.f;
        for (int d = 0; d < D; ++d) {
            float qd = Qs[r][d];
            #pragma unroll
            for (int jj = 0; jj < 16; ++jj)
                s[jj] = fmaf(qd, Ks[j0 + jj][d], s[jj]);
        }
        const int kbase = kt * BKV;
        #pragma unroll
        for (int jj = 0; jj < 16; ++jj) {
            float sv = s[jj] * scale;
            if (kbase + j0 + jj > qrow) sv = -INFINITY;  // causal mask
            Ss[r][j0 + jj] = sv;
        }
        __syncthreads();

        // online softmax update (4 threads per row compute redundantly)
        float tm = -INFINITY;
        for (int j = 0; j < BKV; ++j) tm = fmaxf(tm, Ss[r][j]);
        float newm = fmaxf(m, tm);
        float corr = expf(m - newm);      // 0 on first tile (m = -inf)
        l *= corr;
        #pragma unroll
        for (int i = 0; i < 16; ++i) oacc[i] *= corr;
        for (int j = 0; j < BKV; ++j) {
            float p = expf(Ss[r][j] - newm);
            l += p;
            #pragma unroll
            for (int dd = 0; dd < 16; ++dd)
                oacc[dd] = fmaf(p, Vs[j][d0 + dd], oacc[dd]);
        }
        m = newm;
        __syncthreads();
    }

    const float inv = 1.f / l;
    #pragma unroll
    for (int dd = 0; dd < 16; ++dd)
        o[base + (size_t)qrow * C_ + d0 + dd] = oacc[dd] * inv;
}

// ---------------------------------------------------------------------------
// Launch: q=x@Wq, k=x@Wk, v=x@Wv -> attn -> x1 = x + attn@Wproj + bproj (d_out)
//         h1 = relu(x1@W1 + b1) -> out = x1 + h1@W2 + b2 (d_out, in place)
// ---------------------------------------------------------------------------
extern "C" void kernel_launch(void* const* d_in, const int* in_sizes, int n_in,
                              void* d_out, int out_size, void* d_ws, size_t ws_size,
                              hipStream_t stream) {
    const float* x     = (const float*)d_in[0];
    const float* Wq    = (const float*)d_in[1];
    const float* Wk    = (const float*)d_in[2];
    const float* Wv    = (const float*)d_in[3];
    const float* Wproj = (const float*)d_in[4];
    const float* bproj = (const float*)d_in[5];
    const float* W1    = (const float*)d_in[6];
    const float* b1    = (const float*)d_in[7];
    const float* W2    = (const float*)d_in[8];
    const float* b2    = (const float*)d_in[9];
    float* out = (float*)d_out;

    float* ws = (float*)d_ws;
    const size_t MC = (size_t)M_ * C_;       // 4 Mi elements (16 MiB)
    float* q    = ws;
    float* kbuf = ws + MC;
    float* vbuf = ws + 2 * MC;
    float* attn = ws + 3 * MC;
    // h1 [4096, 4096] reuses ws[0 .. 16Mi): q/k/v/attn are dead by then
    float* h1   = ws;

    dim3 blk(256);
    dim3 gC(C_ / 64, M_ / 64);        // N=1024 tiles
    dim3 gF(4 * C_ / 64, M_ / 64);    // N=4096 tiles
    dim3 gA(T_ / 64, H_, B_);

    // QKV projections
    gemm_f32<false, false><<<gC, blk, 0, stream>>>(x, Wq, nullptr, nullptr, q,    M_, C_, C_);
    gemm_f32<false, false><<<gC, blk, 0, stream>>>(x, Wk, nullptr, nullptr, kbuf, M_, C_, C_);
    gemm_f32<false, false><<<gC, blk, 0, stream>>>(x, Wv, nullptr, nullptr, vbuf, M_, C_, C_);

    // causal flash attention
    attn_f32<<<gA, blk, 0, stream>>>(q, kbuf, vbuf, attn);

    // x1 = x + attn @ Wproj + bproj  -> d_out
    gemm_f32<false, true><<<gC, blk, 0, stream>>>(attn, Wproj, bproj, x, out, M_, C_, C_);

    // h1 = relu(x1 @ W1 + b1)
    gemm_f32<true, false><<<gF, blk, 0, stream>>>(out, W1, b1, nullptr, h1, M_, 4 * C_, C_);

    // out = x1 + h1 @ W2 + b2  (in-place residual: each element read-then-written
    // by exactly the same thread -> no race)
    gemm_f32<false, true><<<gC, blk, 0, stream>>>(h1, W2, b2, out, out, M_, C_, 4 * C_);
}

// Round 3
// 462.229 us; speedup vs baseline: 7.0948x; 7.0948x over previous
//
#include <hip/hip_runtime.h>
#include <math.h>
#include <stdint.h>

// Problem constants (B=2, T=2048, C=1024, H=16, hs=64)
#define B_  2
#define T_  2048
#define C_  1024
#define H_  16
#define HS_ 64
#define M_  4096

typedef unsigned short u16;
typedef u16   u16x8 __attribute__((ext_vector_type(8)));
typedef float f32x4 __attribute__((ext_vector_type(4)));

typedef uint32_t __attribute__((address_space(1))) u32_as1;
typedef uint32_t __attribute__((address_space(3))) u32_as3;

// fp32 -> bf16 round-to-nearest-even
__device__ __forceinline__ u16 f2bf(float f) {
    uint32_t u = __float_as_uint(f);
    u = (u + 0x7fffu + ((u >> 16) & 1u)) >> 16;
    return (u16)u;
}

// async global->LDS, 16 B per lane (dest = wave-uniform base + lane*16)
__device__ __forceinline__ void gload_lds16(const void* g, void* l) {
    __builtin_amdgcn_global_load_lds((const u32_as1*)g, (u32_as3*)l, 16, 0, 0);
}

// D = A(16x32) * B(32x16) + C via inline asm (avoids builtin operand-type drift)
__device__ __forceinline__ f32x4 mfma_bf16(u16x8 a, u16x8 b, f32x4 c) {
    asm("v_mfma_f32_16x16x32_bf16 %0, %1, %2, %0" : "+v"(c) : "v"(a), "v"(b));
    return c;
}

// ---------------------------------------------------------------------------
// Prep kernels: bf16 cast + weight transpose ([K][N] f32 -> [N][K] bf16)
// ---------------------------------------------------------------------------
__global__ __launch_bounds__(256)
void cast_f32_bf16(const float* __restrict__ x, u16* __restrict__ xb) {
    const int i = blockIdx.x * 256 + threadIdx.x;
    const float4* xi = (const float4*)x;
    float4 a = xi[2 * i], b = xi[2 * i + 1];
    u16x8 o;
    o[0] = f2bf(a.x); o[1] = f2bf(a.y); o[2] = f2bf(a.z); o[3] = f2bf(a.w);
    o[4] = f2bf(b.x); o[5] = f2bf(b.y); o[6] = f2bf(b.z); o[7] = f2bf(b.w);
    *(u16x8*)&xb[(size_t)i * 8] = o;
}

__global__ __launch_bounds__(256)
void transpose_cast(const float* __restrict__ W, u16* __restrict__ Wt, int K, int N) {
    __shared__ float tile[64][65];
    const int n0 = blockIdx.x * 64, k0 = blockIdx.y * 64;
    const int tid = threadIdx.x;
    #pragma unroll
    for (int p = 0; p < 16; ++p) {
        int idx = p * 256 + tid;
        int r = idx >> 6, c = idx & 63;
        tile[r][c] = W[(size_t)(k0 + r) * N + n0 + c];
    }
    __syncthreads();
    #pragma unroll
    for (int p = 0; p < 16; ++p) {
        int idx = p * 256 + tid;
        int r = idx >> 6, c = idx & 63;   // r: Wt row (n), c: k
        Wt[(size_t)(n0 + r) * K + k0 + c] = f2bf(tile[c][r]);
    }
}

// 4x [1024][1024] transposes in one launch (Wq,Wk,Wv,Wproj -> contiguous dst)
__global__ __launch_bounds__(256)
void transpose4_cast(const float* __restrict__ A0, const float* __restrict__ A1,
                     const float* __restrict__ A2, const float* __restrict__ A3,
                     u16* __restrict__ Wt) {
    __shared__ float tile[64][65];
    const float* src = (blockIdx.z == 0) ? A0 : (blockIdx.z == 1) ? A1
                     : (blockIdx.z == 2) ? A2 : A3;
    u16* dst = Wt + (size_t)blockIdx.z * 1048576;
    const int n0 = blockIdx.x * 64, k0 = blockIdx.y * 64;
    const int tid = threadIdx.x;
    #pragma unroll
    for (int p = 0; p < 16; ++p) {
        int idx = p * 256 + tid;
        int r = idx >> 6, c = idx & 63;
        tile[r][c] = src[(size_t)(k0 + r) * 1024 + n0 + c];
    }
    __syncthreads();
    #pragma unroll
    for (int p = 0; p < 16; ++p) {
        int idx = p * 256 + tid;
        int r = idx >> 6, c = idx & 63;
        dst[(size_t)(n0 + r) * 1024 + k0 + c] = f2bf(tile[c][r]);
    }
}

// ---------------------------------------------------------------------------
// bf16 MFMA GEMM: Y = A[M,K] @ Bt[N,K]^T, 128x128 tile, BK=64, 256 threads.
// LDS staged with global_load_lds(16B) + XOR chunk swizzle (linear dest,
// inverse-swizzled global source, swizzled read -> 2-way conflicts = free).
// ---------------------------------------------------------------------------
enum { EP_QKV = 0, EP_PROJ = 1, EP_RELU = 2, EP_RESID = 3 };

template<int EP>
__global__ __launch_bounds__(256)
void gemm_bf16(const u16* __restrict__ A, const u16* __restrict__ Bt,
               const float* __restrict__ bias, const float* __restrict__ resid,
               float* __restrict__ fout, u16* __restrict__ bout,
               int N, int K) {
    __shared__ __align__(16) u16 Al[128 * 64];
    __shared__ __align__(16) u16 Bl[128 * 64];
    const int tid  = threadIdx.x;
    const int lane = tid & 63, w = tid >> 6;
    const int wr = w >> 1, wc = w & 1;
    const int brow = blockIdx.y * 128, bcol = blockIdx.x * 128;
    const int rg   = lane >> 3;             // row within 8-row segment
    const int csrc = (lane & 7) ^ rg;       // inverse-swizzled source chunk

    f32x4 acc[4][4];
    #pragma unroll
    for (int i = 0; i < 4; ++i)
        #pragma unroll
        for (int j = 0; j < 4; ++j)
            acc[i][j] = f32x4{0.f, 0.f, 0.f, 0.f};

    for (int k0 = 0; k0 < K; k0 += 64) {
        #pragma unroll
        for (int i = 0; i < 4; ++i) {
            const int seg = i * 4 + w;      // 0..15, wave-uniform
            gload_lds16(A  + (size_t)(brow + seg * 8 + rg) * K + k0 + csrc * 8,
                        &Al[seg * 512]);
            gload_lds16(Bt + (size_t)(bcol + seg * 8 + rg) * K + k0 + csrc * 8,
                        &Bl[seg * 512]);
        }
        __syncthreads();   // drains vmcnt -> LDS tiles ready
        #pragma unroll
        for (int kk = 0; kk < 2; ++kk) {
            u16x8 af[4], bfv[4];
            #pragma unroll
            for (int mi = 0; mi < 4; ++mi) {
                const int row = wr * 64 + mi * 16 + (lane & 15);
                const int ch  = (kk * 4 + (lane >> 4)) ^ (row & 7);
                af[mi] = *(const u16x8*)&Al[row * 64 + ch * 8];
            }
            #pragma unroll
            for (int nj = 0; nj < 4; ++nj) {
                const int row = wc * 64 + nj * 16 + (lane & 15);
                const int ch  = (kk * 4 + (lane >> 4)) ^ (row & 7);
                bfv[nj] = *(const u16x8*)&Bl[row * 64 + ch * 8];
            }
            #pragma unroll
            for (int mi = 0; mi < 4; ++mi)
                #pragma unroll
                for (int nj = 0; nj < 4; ++nj)
                    acc[mi][nj] = mfma_bf16(af[mi], bfv[nj], acc[mi][nj]);
        }
        __syncthreads();
    }

    // Epilogue. D layout: col = lane&15, row = (lane>>4)*4 + r
    const int g = lane >> 4, c16 = lane & 15;
    #pragma unroll
    for (int mi = 0; mi < 4; ++mi) {
        #pragma unroll
        for (int nj = 0; nj < 4; ++nj) {
            #pragma unroll
            for (int r = 0; r < 4; ++r) {
                const int row = brow + wr * 64 + mi * 16 + g * 4 + r;
                const int col = bcol + wc * 64 + nj * 16 + c16;
                const float vacc = acc[mi][nj][r];
                if (EP == EP_QKV) {
                    // scatter to q/k/v in [B,H,T,64] layout
                    const int bb = row >> 11, t = row & 2047;
                    const int region = col >> 10, c = col & 1023;
                    const int hh = c >> 6, d = c & 63;
                    bout[(size_t)region * 4194304 +
                         (((size_t)(bb * 16 + hh)) * 2048 + t) * 64 + d] = f2bf(vacc);
                } else if (EP == EP_PROJ) {
                    const float o = vacc + bias[col] + resid[(size_t)row * N + col];
                    fout[(size_t)row * N + col] = o;
                    bout[(size_t)row * N + col] = f2bf(o);
                } else if (EP == EP_RELU) {
                    float o = vacc + bias[col];
                    o = fmaxf(o, 0.f);
                    bout[(size_t)row * N + col] = f2bf(o);
                } else { // EP_RESID: in-place residual on fout (same thread RMW)
                    const float o = vacc + bias[col] + fout[(size_t)row * N + col];
                    fout[(size_t)row * N + col] = o;
                }
            }
        }
    }
}

// ---------------------------------------------------------------------------
// bf16 MFMA flash attention (causal). Block = (q-tile 64, head, batch),
// 4 waves x 16 q-rows. K tile [64][64+8] LDS, V transposed [64d][64key+8],
// P via per-wave LDS [16][64+8]. scale = 1024^-0.5.
// ---------------------------------------------------------------------------
__global__ __launch_bounds__(256)
void attn_mfma(const u16* __restrict__ q, const u16* __restrict__ k,
               const u16* __restrict__ v, u16* __restrict__ o) {
    __shared__ __align__(16) u16 Kl[64 * 72];
    __shared__ __align__(16) u16 Vt[64 * 72];
    __shared__ __align__(16) u16 Pl[4 * 16 * 72];
    const int tid = threadIdx.x, lane = tid & 63, w = tid >> 6;
    const int g = lane >> 4, c16 = lane & 15;
    const int qt = blockIdx.x, h = blockIdx.y, b = blockIdx.z;
    const float scale = 0.03125f;

    const size_t hb = ((size_t)b * H_ + h) * T_ * HS_;
    const u16* qh = q + hb;
    const u16* kh = k + hb;
    const u16* vh = v + hb;

    // Q fragments (A-frag: row = lane&15, k = g*8+reg)
    const size_t qrow_l = (size_t)(qt * 64 + w * 16 + c16);
    u16x8 qf[2];
    qf[0] = *(const u16x8*)&qh[qrow_l * 64 + g * 8];
    qf[1] = *(const u16x8*)&qh[qrow_l * 64 + 32 + g * 8];

    float m_run[4], l_run[4];
    f32x4 oacc[4];
    #pragma unroll
    for (int r = 0; r < 4; ++r) { m_run[r] = -INFINITY; l_run[r] = 0.f; }
    #pragma unroll
    for (int nt = 0; nt < 4; ++nt) oacc[nt] = f32x4{0.f, 0.f, 0.f, 0.f};

    for (int kv = 0; kv <= qt; ++kv) {
        __syncthreads();  // previous tile fully consumed
        // stage K (row-major, padded) and V transposed
        #pragma unroll
        for (int p = 0; p < 2; ++p) {
            const int idx = p * 256 + tid;
            const int key = idx >> 3, d0 = (idx & 7) * 8;
            u16x8 kvv = *(const u16x8*)&kh[(size_t)(kv * 64 + key) * 64 + d0];
            *(u16x8*)&Kl[key * 72 + d0] = kvv;
            u16x8 vv = *(const u16x8*)&vh[(size_t)(kv * 64 + key) * 64 + d0];
            #pragma unroll
            for (int ii = 0; ii < 8; ++ii) Vt[(d0 + ii) * 72 + key] = vv[ii];
        }
        __syncthreads();

        // S = Q K^T  (4 key-tiles of 16)
        f32x4 s[4];
        #pragma unroll
        for (int kt = 0; kt < 4; ++kt) s[kt] = f32x4{0.f, 0.f, 0.f, 0.f};
        #pragma unroll
        for (int kt = 0; kt < 4; ++kt)
            #pragma unroll
            for (int kk = 0; kk < 2; ++kk) {
                u16x8 kf = *(const u16x8*)&Kl[(kt * 16 + c16) * 72 + kk * 32 + g * 8];
                s[kt] = mfma_bf16(qf[kk], kf, s[kt]);
            }

        // scale + causal mask (only diagonal tile needs it)
        const bool last = (kv == qt);
        float sv[4][4];
        #pragma unroll
        for (int kt = 0; kt < 4; ++kt)
            #pragma unroll
            for (int r = 0; r < 4; ++r) {
                float val = s[kt][r] * scale;
                if (last && (kv * 64 + kt * 16 + c16) > (qt * 64 + w * 16 + g * 4 + r))
                    val = -INFINITY;
                sv[kt][r] = val;
            }

        // row max (reduce over the 16 lanes holding the same rows)
        float pm[4];
        #pragma unroll
        for (int r = 0; r < 4; ++r)
            pm[r] = fmaxf(fmaxf(sv[0][r], sv[1][r]), fmaxf(sv[2][r], sv[3][r]));
        #pragma unroll
        for (int mask = 1; mask < 16; mask <<= 1)
            #pragma unroll
            for (int r = 0; r < 4; ++r)
                pm[r] = fmaxf(pm[r], __shfl_xor(pm[r], mask));

        float corr[4];
        #pragma unroll
        for (int r = 0; r < 4; ++r) {
            const float nm = fmaxf(m_run[r], pm[r]);
            corr[r] = expf(m_run[r] - nm);   // 0 on first tile
            m_run[r] = nm;
        }

        // p = exp(s - m), row-sum, write P to per-wave LDS (bf16)
        float rs[4] = {0.f, 0.f, 0.f, 0.f};
        float ps[4][4];
        #pragma unroll
        for (int kt = 0; kt < 4; ++kt)
            #pragma unroll
            for (int r = 0; r < 4; ++r) {
                const float p = expf(sv[kt][r] - m_run[r]);
                ps[kt][r] = p;
                rs[r] += p;
            }
        #pragma unroll
        for (int mask = 1; mask < 16; mask <<= 1)
            #pragma unroll
            for (int r = 0; r < 4; ++r)
                rs[r] += __shfl_xor(rs[r], mask);
        #pragma unroll
        for (int r = 0; r < 4; ++r) l_run[r] = l_run[r] * corr[r] + rs[r];
        #pragma unroll
        for (int nt = 0; nt < 4; ++nt)
            #pragma unroll
            for (int r = 0; r < 4; ++r) oacc[nt][r] *= corr[r];

        #pragma unroll
        for (int kt = 0; kt < 4; ++kt)
            #pragma unroll
            for (int r = 0; r < 4; ++r)
                Pl[w * 1152 + (g * 4 + r) * 72 + kt * 16 + c16] = f2bf(ps[kt][r]);

        // O += P V  (a-frag from Pl, b-frag from Vt)
        #pragma unroll
        for (int kkp = 0; kkp < 2; ++kkp) {
            u16x8 pf = *(const u16x8*)&Pl[w * 1152 + c16 * 72 + kkp * 32 + g * 8];
            #pragma unroll
            for (int nt = 0; nt < 4; ++nt) {
                u16x8 vf = *(const u16x8*)&Vt[(nt * 16 + c16) * 72 + kkp * 32 + g * 8];
                oacc[nt] = mfma_bf16(pf, vf, oacc[nt]);
            }
        }
    }

    // epilogue: o[b, t, h*64+d] bf16 in [M, C] layout
    float inv[4];
    #pragma unroll
    for (int r = 0; r < 4; ++r) inv[r] = 1.f / l_run[r];
    const int orow = qt * 64 + w * 16;
    #pragma unroll
    for (int nt = 0; nt < 4; ++nt)
        #pragma unroll
        for (int r = 0; r < 4; ++r)
            o[((size_t)(b * T_ + orow + g * 4 + r)) * C_ + h * 64 + nt * 16 + c16] =
                f2bf(oacc[nt][r] * inv[r]);
}

// ---------------------------------------------------------------------------
// Orchestration. ws layout (u16 elems, 64 MiB total):
//   [0)        Wqkvt  [3072][1024]          3,145,728
//   [3145728)  Wpt    [1024][1024]          1,048,576
//   [4194304)  W1t    [4096][1024]          4,194,304
//   [8388608)  W2t    [1024][4096]          4,194,304
//   [12582912) xb     [4096][1024]          4,194,304   (reused as x1b)
//   [16777216) q/k/v  3x[B,H,T,64]         12,582,912   (reused as h1b)
//   [29360128) ab     [4096][1024]          4,194,304
// ---------------------------------------------------------------------------
extern "C" void kernel_launch(void* const* d_in, const int* in_sizes, int n_in,
                              void* d_out, int out_size, void* d_ws, size_t ws_size,
                              hipStream_t stream) {
    const float* x     = (const float*)d_in[0];
    const float* Wq    = (const float*)d_in[1];
    const float* Wk    = (const float*)d_in[2];
    const float* Wv    = (const float*)d_in[3];
    const float* Wproj = (const float*)d_in[4];
    const float* bproj = (const float*)d_in[5];
    const float* W1    = (const float*)d_in[6];
    const float* b1    = (const float*)d_in[7];
    const float* W2    = (const float*)d_in[8];
    const float* b2    = (const float*)d_in[9];
    float* out = (float*)d_out;

    u16* ws    = (u16*)d_ws;
    u16* Wqkvt = ws;
    u16* Wpt   = ws + 3145728;
    u16* W1t   = ws + 4194304;
    u16* W2t   = ws + 8388608;
    u16* xb    = ws + 12582912;
    u16* qb    = ws + 16777216;
    u16* ab    = ws + 29360128;
    u16* x1b   = xb;   // xb dead after QKV gemm
    u16* h1b   = qb;   // q/k/v + ab dead after proj gemm

    dim3 blk(256);

    // prep: casts + weight transposes
    cast_f32_bf16<<<dim3(2048), blk, 0, stream>>>(x, xb);
    transpose4_cast<<<dim3(16, 16, 4), blk, 0, stream>>>(Wq, Wk, Wv, Wproj, Wqkvt);
    transpose_cast<<<dim3(64, 16), blk, 0, stream>>>(W1, W1t, 1024, 4096);
    transpose_cast<<<dim3(16, 64), blk, 0, stream>>>(W2, W2t, 4096, 1024);

    // q/k/v = x @ [Wq|Wk|Wv], scattered to [B,H,T,64]
    gemm_bf16<EP_QKV><<<dim3(24, 32), blk, 0, stream>>>(
        xb, Wqkvt, nullptr, nullptr, nullptr, qb, 3072, 1024);

    // causal flash attention -> ab [M, C] bf16
    attn_mfma<<<dim3(32, 16, 2), blk, 0, stream>>>(
        qb, qb + 4194304, qb + 8388608, ab);

    // x1 = x + attn @ Wproj + bproj  (fp32 -> d_out, bf16 -> x1b)
    gemm_bf16<EP_PROJ><<<dim3(8, 32), blk, 0, stream>>>(
        ab, Wpt, bproj, x, out, x1b, 1024, 1024);

    // h1 = relu(x1 @ W1 + b1) -> bf16
    gemm_bf16<EP_RELU><<<dim3(32, 32), blk, 0, stream>>>(
        x1b, W1t, b1, nullptr, nullptr, h1b, 4096, 1024);

    // out = x1 + h1 @ W2 + b2 (in-place residual on d_out)
    gemm_bf16<EP_RESID><<<dim3(8, 32), blk, 0, stream>>>(
        h1b, W2t, b2, nullptr, out, nullptr, 1024, 4096);
}

// Round 4
// 358.142 us; speedup vs baseline: 9.1567x; 1.2906x over previous
//
#include <hip/hip_runtime.h>
#include <math.h>
#include <stdint.h>

// Problem constants (B=2, T=2048, C=1024, H=16, hs=64)
#define B_  2
#define T_  2048
#define C_  1024
#define H_  16
#define HS_ 64
#define M_  4096

typedef unsigned short u16;
typedef u16   u16x4 __attribute__((ext_vector_type(4)));
typedef u16   u16x8 __attribute__((ext_vector_type(8)));
typedef float f32x4 __attribute__((ext_vector_type(4)));

typedef uint32_t __attribute__((address_space(1))) u32_as1;
typedef uint32_t __attribute__((address_space(3))) u32_as3;

// fp32 -> bf16 round-to-nearest-even
__device__ __forceinline__ u16 f2bf(float f) {
    uint32_t u = __float_as_uint(f);
    u = (u + 0x7fffu + ((u >> 16) & 1u)) >> 16;
    return (u16)u;
}

// async global->LDS, 16 B per lane (dest = wave-uniform base + lane*16)
__device__ __forceinline__ void gload_lds16(const void* g, void* l) {
    __builtin_amdgcn_global_load_lds((const u32_as1*)g, (u32_as3*)l, 16, 0, 0);
}

// D = A(16x32) * B(32x16) + C
__device__ __forceinline__ f32x4 mfma_bf16(u16x8 a, u16x8 b, f32x4 c) {
    asm("v_mfma_f32_16x16x32_bf16 %0, %1, %2, %0" : "+v"(c) : "v"(a), "v"(b));
    return c;
}

// ---------------------------------------------------------------------------
// Prep kernels
// ---------------------------------------------------------------------------
__global__ __launch_bounds__(256)
void cast_f32_bf16(const float* __restrict__ x, u16* __restrict__ xb) {
    const int i = blockIdx.x * 256 + threadIdx.x;
    const float4* xi = (const float4*)x;
    float4 a = xi[2 * i], b = xi[2 * i + 1];
    u16x8 o;
    o[0] = f2bf(a.x); o[1] = f2bf(a.y); o[2] = f2bf(a.z); o[3] = f2bf(a.w);
    o[4] = f2bf(b.x); o[5] = f2bf(b.y); o[6] = f2bf(b.z); o[7] = f2bf(b.w);
    *(u16x8*)&xb[(size_t)i * 8] = o;
}

__global__ __launch_bounds__(256)
void transpose_cast(const float* __restrict__ W, u16* __restrict__ Wt, int K, int N) {
    __shared__ float tile[64][65];
    const int n0 = blockIdx.x * 64, k0 = blockIdx.y * 64;
    const int tid = threadIdx.x;
    #pragma unroll
    for (int p = 0; p < 16; ++p) {
        int idx = p * 256 + tid;
        int r = idx >> 6, c = idx & 63;
        tile[r][c] = W[(size_t)(k0 + r) * N + n0 + c];
    }
    __syncthreads();
    #pragma unroll
    for (int p = 0; p < 16; ++p) {
        int idx = p * 256 + tid;
        int r = idx >> 6, c = idx & 63;
        Wt[(size_t)(n0 + r) * K + k0 + c] = f2bf(tile[c][r]);
    }
}

__global__ __launch_bounds__(256)
void transpose4_cast(const float* __restrict__ A0, const float* __restrict__ A1,
                     const float* __restrict__ A2, const float* __restrict__ A3,
                     u16* __restrict__ Wt) {
    __shared__ float tile[64][65];
    const float* src = (blockIdx.z == 0) ? A0 : (blockIdx.z == 1) ? A1
                     : (blockIdx.z == 2) ? A2 : A3;
    u16* dst = Wt + (size_t)blockIdx.z * 1048576;
    const int n0 = blockIdx.x * 64, k0 = blockIdx.y * 64;
    const int tid = threadIdx.x;
    #pragma unroll
    for (int p = 0; p < 16; ++p) {
        int idx = p * 256 + tid;
        int r = idx >> 6, c = idx & 63;
        tile[r][c] = src[(size_t)(k0 + r) * 1024 + n0 + c];
    }
    __syncthreads();
    #pragma unroll
    for (int p = 0; p < 16; ++p) {
        int idx = p * 256 + tid;
        int r = idx >> 6, c = idx & 63;
        dst[(size_t)(n0 + r) * 1024 + k0 + c] = f2bf(tile[c][r]);
    }
}

// ---------------------------------------------------------------------------
// bf16 MFMA GEMM: Y = A[M,K] @ Bt[N,K]^T, 128x128 tile, BK=64, 256 threads.
// EP_QKV scatters q,k -> [B,H,T,64] and v -> [B,H,64,T] (transposed, packed).
// ---------------------------------------------------------------------------
enum { EP_QKV = 0, EP_PROJ = 1, EP_RELU = 2, EP_RESID = 3 };

template<int EP>
__global__ __launch_bounds__(256)
void gemm_bf16(const u16* __restrict__ A, const u16* __restrict__ Bt,
               const float* __restrict__ bias, const float* __restrict__ resid,
               float* __restrict__ fout, u16* __restrict__ bout,
               int N, int K) {
    __shared__ __align__(16) u16 Al[128 * 64];
    __shared__ __align__(16) u16 Bl[128 * 64];
    const int tid  = threadIdx.x;
    const int lane = tid & 63, w = tid >> 6;
    const int wr = w >> 1, wc = w & 1;
    const int brow = blockIdx.y * 128, bcol = blockIdx.x * 128;
    const int rg   = lane >> 3;
    const int csrc = (lane & 7) ^ rg;

    f32x4 acc[4][4];
    #pragma unroll
    for (int i = 0; i < 4; ++i)
        #pragma unroll
        for (int j = 0; j < 4; ++j)
            acc[i][j] = f32x4{0.f, 0.f, 0.f, 0.f};

    for (int k0 = 0; k0 < K; k0 += 64) {
        #pragma unroll
        for (int i = 0; i < 4; ++i) {
            const int seg = i * 4 + w;
            gload_lds16(A  + (size_t)(brow + seg * 8 + rg) * K + k0 + csrc * 8,
                        &Al[seg * 512]);
            gload_lds16(Bt + (size_t)(bcol + seg * 8 + rg) * K + k0 + csrc * 8,
                        &Bl[seg * 512]);
        }
        __syncthreads();
        #pragma unroll
        for (int kk = 0; kk < 2; ++kk) {
            u16x8 af[4], bfv[4];
            #pragma unroll
            for (int mi = 0; mi < 4; ++mi) {
                const int row = wr * 64 + mi * 16 + (lane & 15);
                const int ch  = (kk * 4 + (lane >> 4)) ^ (row & 7);
                af[mi] = *(const u16x8*)&Al[row * 64 + ch * 8];
            }
            #pragma unroll
            for (int nj = 0; nj < 4; ++nj) {
                const int row = wc * 64 + nj * 16 + (lane & 15);
                const int ch  = (kk * 4 + (lane >> 4)) ^ (row & 7);
                bfv[nj] = *(const u16x8*)&Bl[row * 64 + ch * 8];
            }
            #pragma unroll
            for (int mi = 0; mi < 4; ++mi)
                #pragma unroll
                for (int nj = 0; nj < 4; ++nj)
                    acc[mi][nj] = mfma_bf16(af[mi], bfv[nj], acc[mi][nj]);
        }
        __syncthreads();
    }

    // Epilogue. D layout: col = lane&15, row = (lane>>4)*4 + r
    const int g = lane >> 4, c16 = lane & 15;
    #pragma unroll
    for (int mi = 0; mi < 4; ++mi) {
        #pragma unroll
        for (int nj = 0; nj < 4; ++nj) {
            if (EP == EP_QKV) {
                const int col = bcol + wc * 64 + nj * 16 + c16;
                const int region = col >> 10, c = col & 1023;
                const int hh = c >> 6, d = c & 63;
                const int row0 = brow + wr * 64 + mi * 16 + g * 4;
                const int bb = row0 >> 11, t0 = row0 & 2047;
                if (region < 2) {   // q,k: [B,H,T,64]
                    #pragma unroll
                    for (int r = 0; r < 4; ++r)
                        bout[(size_t)region * 4194304 +
                             (((size_t)(bb * 16 + hh)) * 2048 + t0 + r) * 64 + d] =
                            f2bf(acc[mi][nj][r]);
                } else {            // v: [B,H,64,T] transposed, packed 8B
                    u16x4 pk;
                    #pragma unroll
                    for (int r = 0; r < 4; ++r) pk[r] = f2bf(acc[mi][nj][r]);
                    *(u16x4*)&bout[(size_t)2 * 4194304 +
                                   (((size_t)(bb * 16 + hh)) * 64 + d) * 2048 + t0] = pk;
                }
            } else {
                #pragma unroll
                for (int r = 0; r < 4; ++r) {
                    const int row = brow + wr * 64 + mi * 16 + g * 4 + r;
                    const int col = bcol + wc * 64 + nj * 16 + c16;
                    const float vacc = acc[mi][nj][r];
                    if (EP == EP_PROJ) {
                        const float o = vacc + bias[col] + resid[(size_t)row * N + col];
                        fout[(size_t)row * N + col] = o;
                        bout[(size_t)row * N + col] = f2bf(o);
                    } else if (EP == EP_RELU) {
                        float o = vacc + bias[col];
                        o = fmaxf(o, 0.f);
                        bout[(size_t)row * N + col] = f2bf(o);
                    } else { // EP_RESID
                        const float o = vacc + bias[col] + fout[(size_t)row * N + col];
                        fout[(size_t)row * N + col] = o;
                    }
                }
            }
        }
    }
}

// ---------------------------------------------------------------------------
// bf16 MFMA flash attention (causal), load-balanced:
// block = (pair, head, batch) handles q-tiles {pair, 31-pair} -> constant
// 33 kv-tiles/block. K staged [64][64] + XOR chunk swizzle via global_load_lds;
// V pre-transposed globally [B,H,64,T], staged the same way. P via per-wave
// padded LDS. scale = 1024^-0.5. __expf softmax.
// ---------------------------------------------------------------------------
__global__ __launch_bounds__(256)
void attn_mfma(const u16* __restrict__ q, const u16* __restrict__ k,
               const u16* __restrict__ vt, u16* __restrict__ o) {
    __shared__ __align__(16) u16 Kl[64 * 64];
    __shared__ __align__(16) u16 Vl[64 * 64];
    __shared__ __align__(16) u16 Pl[4 * 16 * 72];
    const int tid = threadIdx.x, lane = tid & 63, w = tid >> 6;
    const int g = lane >> 4, c16 = lane & 15;
    const int rg = lane >> 3, csrc = (lane & 7) ^ rg;
    const int pair = blockIdx.x, h = blockIdx.y, b = blockIdx.z;
    const float scale = 0.03125f;  // 1024^-0.5

    const size_t hb  = ((size_t)b * H_ + h) * T_ * HS_;   // q,k: [B,H,T,64]
    const u16* qh = q  + hb;
    const u16* kh = k  + hb;
    const u16* vh = vt + hb;                              // v: [B,H,64,T]

    #pragma unroll
    for (int phase = 0; phase < 2; ++phase) {
        const int qt = phase ? (31 - pair) : pair;

        // Q fragments (A-frag: row = lane&15, k = g*8+reg)
        const size_t qrow_l = (size_t)(qt * 64 + w * 16 + c16);
        u16x8 qf[2];
        qf[0] = *(const u16x8*)&qh[qrow_l * 64 + g * 8];
        qf[1] = *(const u16x8*)&qh[qrow_l * 64 + 32 + g * 8];

        float m_run[4], l_run[4];
        f32x4 oacc[4];
        #pragma unroll
        for (int r = 0; r < 4; ++r) { m_run[r] = -INFINITY; l_run[r] = 0.f; }
        #pragma unroll
        for (int nt = 0; nt < 4; ++nt) oacc[nt] = f32x4{0.f, 0.f, 0.f, 0.f};

        for (int kv = 0; kv <= qt; ++kv) {
            __syncthreads();  // previous tile fully consumed
            #pragma unroll
            for (int i = 0; i < 2; ++i) {
                const int seg = i * 4 + w;   // 0..7, wave-uniform
                gload_lds16(kh + (size_t)(kv * 64 + seg * 8 + rg) * 64 + csrc * 8,
                            &Kl[seg * 512]);
                gload_lds16(vh + (size_t)(seg * 8 + rg) * T_ + kv * 64 + csrc * 8,
                            &Vl[seg * 512]);
            }
            __syncthreads();  // drains vmcnt

            // S = Q K^T  (4 key-tiles of 16)
            f32x4 s[4];
            #pragma unroll
            for (int kt = 0; kt < 4; ++kt) s[kt] = f32x4{0.f, 0.f, 0.f, 0.f};
            #pragma unroll
            for (int kt = 0; kt < 4; ++kt)
                #pragma unroll
                for (int kk = 0; kk < 2; ++kk) {
                    const int row = kt * 16 + c16;
                    const int ch  = (kk * 4 + g) ^ (row & 7);
                    u16x8 kf = *(const u16x8*)&Kl[row * 64 + ch * 8];
                    s[kt] = mfma_bf16(qf[kk], kf, s[kt]);
                }

            // scale + causal mask (only diagonal tile)
            const bool last = (kv == qt);
            float sv[4][4];
            #pragma unroll
            for (int kt = 0; kt < 4; ++kt)
                #pragma unroll
                for (int r = 0; r < 4; ++r) {
                    float val = s[kt][r] * scale;
                    if (last && (kv * 64 + kt * 16 + c16) > (qt * 64 + w * 16 + g * 4 + r))
                        val = -INFINITY;
                    sv[kt][r] = val;
                }

            // row max across the 16 lanes holding each row
            float pm[4];
            #pragma unroll
            for (int r = 0; r < 4; ++r)
                pm[r] = fmaxf(fmaxf(sv[0][r], sv[1][r]), fmaxf(sv[2][r], sv[3][r]));
            #pragma unroll
            for (int mask = 1; mask < 16; mask <<= 1)
                #pragma unroll
                for (int r = 0; r < 4; ++r)
                    pm[r] = fmaxf(pm[r], __shfl_xor(pm[r], mask));

            float corr[4];
            #pragma unroll
            for (int r = 0; r < 4; ++r) {
                const float nm = fmaxf(m_run[r], pm[r]);
                corr[r] = __expf(m_run[r] - nm);   // 0 on first tile
                m_run[r] = nm;
            }

            float rs[4] = {0.f, 0.f, 0.f, 0.f};
            float ps[4][4];
            #pragma unroll
            for (int kt = 0; kt < 4; ++kt)
                #pragma unroll
                for (int r = 0; r < 4; ++r) {
                    const float p = __expf(sv[kt][r] - m_run[r]);
                    ps[kt][r] = p;
                    rs[r] += p;
                }
            #pragma unroll
            for (int mask = 1; mask < 16; mask <<= 1)
                #pragma unroll
                for (int r = 0; r < 4; ++r)
                    rs[r] += __shfl_xor(rs[r], mask);
            #pragma unroll
            for (int r = 0; r < 4; ++r) l_run[r] = l_run[r] * corr[r] + rs[r];
            #pragma unroll
            for (int nt = 0; nt < 4; ++nt)
                #pragma unroll
                for (int r = 0; r < 4; ++r) oacc[nt][r] *= corr[r];

            #pragma unroll
            for (int kt = 0; kt < 4; ++kt)
                #pragma unroll
                for (int r = 0; r < 4; ++r)
                    Pl[w * 1152 + (g * 4 + r) * 72 + kt * 16 + c16] = f2bf(ps[kt][r]);

            // O += P V
            #pragma unroll
            for (int kkp = 0; kkp < 2; ++kkp) {
                u16x8 pf = *(const u16x8*)&Pl[w * 1152 + c16 * 72 + kkp * 32 + g * 8];
                #pragma unroll
                for (int nt = 0; nt < 4; ++nt) {
                    const int row = nt * 16 + c16;          // d
                    const int ch  = (kkp * 4 + g) ^ (row & 7);
                    u16x8 vf = *(const u16x8*)&Vl[row * 64 + ch * 8];
                    oacc[nt] = mfma_bf16(pf, vf, oacc[nt]);
                }
            }
        }

        // epilogue: o[b, t, h*64+d] bf16 in [M, C] layout
        float inv[4];
        #pragma unroll
        for (int r = 0; r < 4; ++r) inv[r] = 1.f / l_run[r];
        const int orow = qt * 64 + w * 16;
        #pragma unroll
        for (int nt = 0; nt < 4; ++nt)
            #pragma unroll
            for (int r = 0; r < 4; ++r)
                o[((size_t)(b * T_ + orow + g * 4 + r)) * C_ + h * 64 + nt * 16 + c16] =
                    f2bf(oacc[nt][r] * inv[r]);
    }
}

// ---------------------------------------------------------------------------
// Orchestration. ws layout (u16 elems, 64 MiB total):
//   [0)        Wqkvt  [3072][1024]          3,145,728
//   [3145728)  Wpt    [1024][1024]          1,048,576
//   [4194304)  W1t    [4096][1024]          4,194,304
//   [8388608)  W2t    [1024][4096]          4,194,304
//   [12582912) xb     [4096][1024]          4,194,304   (reused as x1b)
//   [16777216) q/k/vt 3x[B,H,..]           12,582,912   (reused as h1b)
//   [29360128) ab     [4096][1024]          4,194,304
// ---------------------------------------------------------------------------
extern "C" void kernel_launch(void* const* d_in, const int* in_sizes, int n_in,
                              void* d_out, int out_size, void* d_ws, size_t ws_size,
                              hipStream_t stream) {
    const float* x     = (const float*)d_in[0];
    const float* Wq    = (const float*)d_in[1];
    const float* Wk    = (const float*)d_in[2];
    const float* Wv    = (const float*)d_in[3];
    const float* Wproj = (const float*)d_in[4];
    const float* bproj = (const float*)d_in[5];
    const float* W1    = (const float*)d_in[6];
    const float* b1    = (const float*)d_in[7];
    const float* W2    = (const float*)d_in[8];
    const float* b2    = (const float*)d_in[9];
    float* out = (float*)d_out;

    u16* ws    = (u16*)d_ws;
    u16* Wqkvt = ws;
    u16* Wpt   = ws + 3145728;
    u16* W1t   = ws + 4194304;
    u16* W2t   = ws + 8388608;
    u16* xb    = ws + 12582912;
    u16* qb    = ws + 16777216;
    u16* ab    = ws + 29360128;
    u16* x1b   = xb;   // xb dead after QKV gemm
    u16* h1b   = qb;   // q/k/v + ab dead after proj gemm

    dim3 blk(256);

    cast_f32_bf16<<<dim3(2048), blk, 0, stream>>>(x, xb);
    transpose4_cast<<<dim3(16, 16, 4), blk, 0, stream>>>(Wq, Wk, Wv, Wproj, Wqkvt);
    transpose_cast<<<dim3(64, 16), blk, 0, stream>>>(W1, W1t, 1024, 4096);
    transpose_cast<<<dim3(16, 64), blk, 0, stream>>>(W2, W2t, 4096, 1024);

    // q/k -> [B,H,T,64], v -> [B,H,64,T] (transposed)
    gemm_bf16<EP_QKV><<<dim3(24, 32), blk, 0, stream>>>(
        xb, Wqkvt, nullptr, nullptr, nullptr, qb, 3072, 1024);

    // causal flash attention (load-balanced pairs) -> ab [M, C] bf16
    attn_mfma<<<dim3(16, 16, 2), blk, 0, stream>>>(
        qb, qb + 4194304, qb + 8388608, ab);

    // x1 = x + attn @ Wproj + bproj
    gemm_bf16<EP_PROJ><<<dim3(8, 32), blk, 0, stream>>>(
        ab, Wpt, bproj, x, out, x1b, 1024, 1024);

    // h1 = relu(x1 @ W1 + b1)
    gemm_bf16<EP_RELU><<<dim3(32, 32), blk, 0, stream>>>(
        x1b, W1t, b1, nullptr, nullptr, h1b, 4096, 1024);

    // out = x1 + h1 @ W2 + b2
    gemm_bf16<EP_RESID><<<dim3(8, 32), blk, 0, stream>>>(
        h1b, W2t, b2, nullptr, out, nullptr, 1024, 4096);
}